// Round 11
// baseline (803.586 us; speedup 1.0000x reference)
//
#include <hip/hip_runtime.h>

// Modular readout: 8 modules, each h = relu(x_m @ W1_m^T + b1_m); y_m = h @ W2_m^T + b2_m
// x [8192,4096] fp32; W1 [4096,4096] fp32 block-diag (8x 512x512); W2 [80,4096] fp32 block-diag
// out [8192,80] fp32 row-major (module-major columns).
//
// R16: R15 (W 2-iter deep) flat -> latency-exposure theory dead. Corrected R14 ablation
//      (rule #13: reps 2-3 were cache-warm; cold staging ~= whole kernel) + the identity
//      dur ~= FETCH/hbm_gbps (69.5MB / 940GB/s = 74us ~= 85) -> kernel is HBM-fetch-bound
//      at 940 GB/s (15% of streaming ceiling) ON THE X GATHER PATH (16KB-strided rows,
//      in-loop cvt). Fix: split x into a pure STREAMING pre-pass + fragment-direct GEMM.
//  - cvt_x: sequential fp32 reads (2KB/wave contiguous, the 6.3TB/s pattern) -> 64MB bf16
//    MFMA-fragment-linear xb[(m,tile)][kk][mt][lane] in workspace. Doubles as BW probe.
//  - fused_full2: block = 128 rows x FULL module (512 cols), 512 thr / 8 waves
//    (wave = 128x64 = R8's shape, acc[8][4]); grid 512 -> all blocks resident, 1 round.
//    A-frags REGISTER-DIRECT from xb (1KB contiguous/instr; 8 waves share granules -> L1/L2).
//    No A-LDS, no in-loop cvt. B keeps R8-proven DMA staging (dbuf, src-XOR, pre-barrier
//    drain by issuing wave). Single-writer outputs: NO atomics, NO init_out. Epilogue uses
//    R12's verified XOR-ldsH (64x512, aliases B-LDS). LDS = 65536 B, 2 blocks/CU.
//  - Tier gate: ws >= 72MB -> new path; else tier C legacy.

#define NMOD 8
#define DIM 512
#define OSZ 10
#define BATCH 8192
#define D_IN 4096
#define D_OUT 80
#define BM 128
#define BK 32
#define NK (DIM / BK)     // 16

#define B_ROWS 512
#define B_SZ (B_ROWS * BK)          // 16384 shorts per B buffer (32768 B)
#define XB_SHORTS ((size_t)BATCH * D_IN)          // 33554432 shorts = 64 MB
#define XGRAN (BATCH * D_IN / 8)                  // 4194304 granules

// legacy tier-C sizes
#define LDSA_SZ 5120
#define LDSB_SZ 8192
#define ASTRIDE 40
#define HSTRIDE 264

#define VMCNT(n) asm volatile("s_waitcnt vmcnt(" #n ")" ::: "memory")
#define MEMFENCE() asm volatile("" ::: "memory")

typedef __attribute__((ext_vector_type(8))) short short8;   // 8 bf16 MFMA A/B frag
typedef __attribute__((ext_vector_type(4))) float float4v;  // MFMA C/D frag
typedef __attribute__((ext_vector_type(4))) unsigned int uint4v;

__device__ __forceinline__ unsigned short f2bf(float f) {
    unsigned int u = __builtin_bit_cast(unsigned int, f);
    u += 0x7fffu + ((u >> 16) & 1u);   // RNE
    return (unsigned short)(u >> 16);
}

__device__ __forceinline__ unsigned int pk2(float a, float b) {
    unsigned int r;
    asm("v_cvt_pk_bf16_f32 %0, %1, %2" : "=v"(r) : "v"(a), "v"(b));
    return r;
}

// packed f32x8 -> bf16x8 via HW cvt_pk (RNE, same numerics as f2bf)
__device__ __forceinline__ short8 cvt8(float4 a, float4 b) {
    uint4v u = {pk2(a.x, a.y), pk2(a.z, a.w), pk2(b.x, b.y), pk2(b.z, b.w)};
    return __builtin_bit_cast(short8, u);
}

// ------- tier C init: out = broadcast b2 -------
__global__ void init_out_kernel(const float* __restrict__ b2, float* __restrict__ out) {
    int idx = blockIdx.x * 256 + threadIdx.x;
    out[idx] = b2[idx % D_OUT];
}

// ------- pre-pass 1: x fp32 (sequential read) -> xb bf16 fragment-linear -------
// granule g = (((m*64+tile)*16 + kk)*8 + mt)*64 + kq*16 + r16 holds
//   x[tile*128 + mt*16 + r16][m*512 + kk*32 + kq*8 .. +8] as bf16x8.
// Thread j reads x sequentially (32B), scatters one 16B granule. 16384 x 256 threads.
__global__ void cvt_x_kernel(const float* __restrict__ x, ushort* __restrict__ xb) {
    int j = blockIdx.x * 256 + threadIdx.x;              // 0 .. 4194303
    int row = j >> 9, k8 = j & 511;
    const float* p = x + (size_t)row * D_IN + k8 * 8;
    int m = k8 >> 6, kmod = k8 & 63, kk = kmod >> 2, kq = kmod & 3;
    int tile = row >> 7, mt = (row >> 4) & 7, r16 = row & 15;
    size_t g = ((size_t)(((m * 64 + tile) * 16 + kk) * 8 + mt) << 6) + kq * 16 + r16;
    *(short8*)(xb + g * 8) = cvt8(*(const float4*)p, *(const float4*)(p + 4));
}

// ------- pre-pass 2: W1 diag blocks -> w1b[8][512][512] bf16 (4 MB) -------
__global__ void cvt_w_kernel(const float* __restrict__ W1, ushort* __restrict__ w1b) {
    int j = blockIdx.x * 256 + threadIdx.x;              // 2048*256 = 524288 float4 jobs
    int mm = j >> 16, rem = j & 65535, r = rem >> 7, c4 = rem & 127;
    float4 v = *(const float4*)(W1 + (size_t)(mm * DIM + r) * D_IN + mm * DIM + c4 * 4);
    *(ushort4*)(w1b + (size_t)mm * DIM * DIM + r * DIM + c4 * 4) =
        make_ushort4(f2bf(v.x), f2bf(v.y), f2bf(v.z), f2bf(v.w));
}

// ---------------- R16 fragment-direct fused kernel ----------------
// grid 512: bid = tile*8 + m. block 512 (8 waves); wave w: hidden cols [w*64,+64),
// all 128 batch rows (acc[8][4]).
// LDS 65536 B: B0/B1 dbuf [512][32] shorts; ldsH [64][512] XOR-swizzled (aliased).
__global__ __launch_bounds__(512, 4)
void fused_full2(const ushort* __restrict__ xb, const ushort* __restrict__ w1b,
                 const float* __restrict__ b1, const float* __restrict__ W2,
                 const float* __restrict__ b2, float* __restrict__ out) {
    __shared__ __attribute__((aligned(16))) ushort smem[32768];   // 65536 B
    ushort* B0 = smem;
    ushort* B1 = smem + B_SZ;
    ushort* ldsH = smem;                                  // epilogue alias

    const int tid  = threadIdx.x;
    const int wave = tid >> 6;                            // 0..7 = col group
    const int lane = tid & 63;
    const int r16  = lane & 15;
    const int kq   = lane >> 4;

    const int bid     = blockIdx.x;
    const int m       = bid & 7;                          // module -> XCD round-robin
    const int tile    = bid >> 3;
    const int rowBase = tile * BM;

    const ushort* w1m = w1b + (size_t)m * DIM * DIM;                      // [512][512] bf16
    const ushort* xfb = xb + ((size_t)(m * 64 + tile) << 16) + lane * 8;  // plane + lane

    // W staging mapping: 4 DMA/thread: rows r*128 + (tid>>2), 16B chunk tid&3
    const int brow = tid >> 2;
    const int bc   = tid & 3;

    float4v acc[8][4];
#pragma unroll
    for (int i = 0; i < 8; i++)
#pragma unroll
        for (int j = 0; j < 4; j++) acc[i][j] = (float4v){0.f, 0.f, 0.f, 0.f};

    short8 aC[8], aN[8], bF[4];

    auto issueW = [&](int k, ushort* Bn) {
#pragma unroll
        for (int r = 0; r < 4; r++) {
            const int row = r * 128 + brow;
            const int f   = (row >> 1) & 3;     // src-XOR so linear DMA dst reads conflict-free
            __builtin_amdgcn_global_load_lds(
                (const __attribute__((address_space(1))) void*)(w1m + (size_t)row * DIM + k * BK + (bc ^ f) * 8),
                (__attribute__((address_space(3))) void*)(Bn + row * BK + bc * 8), 16, 0, 0);
        }
    };
    auto issueA = [&](int kk, short8 (&a)[8]) {           // 8 x 1KB contiguous reg loads
        const ushort* p = xfb + kk * 4096;
#pragma unroll
        for (int mt = 0; mt < 8; mt++)
            a[mt] = *(const short8*)(p + mt * 512);
    };
    auto readB = [&](const ushort* Bc) {
#pragma unroll
        for (int nt = 0; nt < 4; nt++) {
            const int row = wave * 64 + nt * 16 + r16;
            bF[nt] = *(const short8*)(Bc + row * BK + (kq ^ ((row >> 1) & 3)) * 8);
        }
    };
    auto mfma = [&](short8 (&a)[8]) {
#pragma unroll
        for (int mt = 0; mt < 8; mt++)
#pragma unroll
            for (int nt = 0; nt < 4; nt++)
                acc[mt][nt] = __builtin_amdgcn_mfma_f32_16x16x32_bf16(a[mt], bF[nt], acc[mt][nt], 0, 0, 0);
    };

    // ---- prologue: W(0) then A(0). VMCNT(8) drains W(0) (cross-wave, pre-barrier);
    //      A(0)'s 8 loads stay in flight (compiler waits before first use). ----
    issueW(0, B0);   MEMFENCE();
    issueA(0, aC);
    VMCNT(8);
    __builtin_amdgcn_s_barrier();
    MEMFENCE();

    // Steady iter k: issueW(k+1) [4, oldest], issueA(k+1) [8]; readB(B(k)); mfma
    // (compiler-inserted vmcnt waits for a-regs); VMCNT(8) drains W(k+1) pre-barrier
    // (issuing wave drains its cross-wave DMAs BEFORE the barrier); s_barrier.
    for (int k2 = 0; k2 < 14; k2 += 2) {
        { // even k: consume B0/aC; W(k+1)->B1, A(k+1)->aN
            issueW(k2 + 1, B1); MEMFENCE();
            issueA(k2 + 1, aN); MEMFENCE();
            readB(B0);
            mfma(aC);
            MEMFENCE();
            VMCNT(8);
            __builtin_amdgcn_s_barrier();
            MEMFENCE();
        }
        { // odd k: consume B1/aN; W(k+2)->B0, A(k+2)->aC
            issueW(k2 + 2, B0); MEMFENCE();
            issueA(k2 + 2, aC); MEMFENCE();
            readB(B1);
            mfma(aN);
            MEMFENCE();
            VMCNT(8);
            __builtin_amdgcn_s_barrier();
            MEMFENCE();
        }
    }
    { // k = 14 (even): last issues W(15)/A(15)
        issueW(15, B1); MEMFENCE();
        issueA(15, aN); MEMFENCE();
        readB(B0);
        mfma(aC);
        MEMFENCE();
        VMCNT(8);
        __builtin_amdgcn_s_barrier();
        MEMFENCE();
    }
    { // k = 15 (odd): no issues
        readB(B1);
        mfma(aN);
        MEMFENCE();
    }

    float b1v[4];
#pragma unroll
    for (int nt = 0; nt < 4; nt++)
        b1v[nt] = b1[m * DIM + wave * 64 + nt * 16 + r16];

    // ---- epilogue: two 64-row halves; h -> XOR-swizzled ldsH [64][512] (R12-verified
    //      convention); layer 2 by waves 0..3; single-writer stores (bias added here). ----
    const float b2v = (r16 < OSZ) ? b2[m * OSZ + r16] : 0.f;
    for (int hh = 0; hh < 2; hh++) {
        __syncthreads();                      // K-loop B reads / prev layer-2 reads done
#pragma unroll
        for (int mt2 = 0; mt2 < 4; mt2++) {
            const int mt = hh * 4 + mt2;
#pragma unroll
            for (int nt = 0; nt < 4; nt++) {
#pragma unroll
                for (int reg = 0; reg < 4; reg++) {
                    float v = acc[mt][nt][reg] + b1v[nt];
                    v = v > 0.f ? v : 0.f;
                    const int lr  = mt2 * 16 + kq * 4 + reg;      // local row 0..63 (lr&1==reg&1)
                    const int col = wave * 64 + nt * 16 + r16;    // hidden col 0..511
                    const int g = col >> 3, c7 = col & 7;
                    ldsH[lr * 512 + ((g ^ ((reg & 1) << 2)) << 3) + c7] = f2bf(v);
                }
            }
        }
        __syncthreads();

        // layer 2: waves 0..3, wave w: y rows [hh*64 + w*16, +16) = h[16][512] @ W2_m^T + b2
        if (wave < 4) {
            float4v acc2 = (float4v){0.f, 0.f, 0.f, 0.f};
            const float* w2row = W2 + (size_t)(m * OSZ + r16) * D_IN + m * DIM;
#pragma unroll
            for (int kc = 0; kc < 16; kc++) {
                const int hrow = wave * 16 + r16;
                const int slot = (kc * 4 + kq) ^ ((r16 & 1) << 2);
                short8 hA = *(const short8*)(ldsH + hrow * 512 + slot * 8);
                short8 wb = {0, 0, 0, 0, 0, 0, 0, 0};
                if (r16 < OSZ) {
                    const float* p = w2row + kc * 32 + kq * 8;
                    wb = cvt8(*(const float4*)p, *(const float4*)(p + 4));
                }
                acc2 = __builtin_amdgcn_mfma_f32_16x16x32_bf16(hA, wb, acc2, 0, 0, 0);
            }
            if (r16 < OSZ) {
#pragma unroll
                for (int reg = 0; reg < 4; reg++) {
                    const int grow = rowBase + hh * 64 + wave * 16 + kq * 4 + reg;
                    out[(size_t)grow * D_OUT + m * OSZ + r16] = acc2[reg] + b2v;
                }
            }
        }
    }
}

// ---------------- legacy fused kernel (tier C fallback, R5 structure) ----------------
__global__ __launch_bounds__(256, 2)
void fused_kernel(const float* __restrict__ x, const float* __restrict__ W1,
                  const float* __restrict__ b1, const float* __restrict__ W2,
                  float* __restrict__ out) {
    __shared__ __attribute__((aligned(16))) ushort smem[26624];   // 53248 B
    ushort* ldsA0 = smem;
    ushort* ldsA1 = smem + LDSA_SZ;
    ushort* ldsB0 = smem + 2 * LDSA_SZ;
    ushort* ldsB1 = smem + 2 * LDSA_SZ + LDSB_SZ;
    ushort* ldsH  = smem;

    const int tid  = threadIdx.x;
    const int wave = tid >> 6;
    const int lane = tid & 63;
    const int r16  = lane & 15;
    const int kq   = lane >> 4;

    const int bid     = blockIdx.x;
    const int m       = bid & 7;
    const int half    = (bid >> 3) & 1;
    const int rowBase = (bid >> 4) * BM;

    const float*  xsrc = x + (size_t)rowBase * D_IN + m * DIM;
    const float*  w1f  = W1 + (size_t)(m * DIM + half * 256) * D_IN + m * DIM;

    const int arow = tid >> 1;
    const int ah   = tid & 1;
    const int brow = tid >> 2;
    const int bc   = tid & 3;

    float4v acc[8][4];
#pragma unroll
    for (int i = 0; i < 8; i++)
#pragma unroll
        for (int j = 0; j < 4; j++) acc[i][j] = (float4v){0.f, 0.f, 0.f, 0.f};

#pragma unroll
    for (int r = 0; r < 4; r++) {
        const int row = r * 64 + brow;
        const int f   = (row >> 1) & 3;
        const float* p = w1f + (size_t)row * D_IN + bc * 8;
        *(short8*)(ldsB0 + row * BK + (bc ^ f) * 8) = cvt8(*(const float4*)p, *(const float4*)(p + 4));
    }
    {
        const float* p = xsrc + (size_t)arow * D_IN + ah * 16;
        float4 a0 = *(const float4*)p, a1 = *(const float4*)(p + 4);
        float4 a2 = *(const float4*)(p + 8), a3 = *(const float4*)(p + 12);
        *(short8*)(ldsA0 + arow * ASTRIDE + ah * 16)     = cvt8(a0, a1);
        *(short8*)(ldsA0 + arow * ASTRIDE + ah * 16 + 8) = cvt8(a2, a3);
    }

    for (int kk = 0; kk < NK; kk++) {
        __syncthreads();
        ushort* Ac = (kk & 1) ? ldsA1 : ldsA0;
        ushort* Bc = (kk & 1) ? ldsB1 : ldsB0;
        ushort* An = (kk & 1) ? ldsA0 : ldsA1;
        ushort* Bn = (kk & 1) ? ldsB0 : ldsB1;

        float4 xr0, xr1, xr2, xr3;
        const bool pf = (kk < NK - 1);
        if (pf) {
            const float* p = xsrc + (size_t)arow * D_IN + kk * BK + BK + ah * 16;
            xr0 = *(const float4*)p;     xr1 = *(const float4*)(p + 4);
            xr2 = *(const float4*)(p + 8); xr3 = *(const float4*)(p + 12);
        }

        short8 aF[8], bF[4];
#pragma unroll
        for (int mt = 0; mt < 8; mt++)
            aF[mt] = *(const short8*)(Ac + (mt * 16 + r16) * ASTRIDE + kq * 8);
#pragma unroll
        for (int nt = 0; nt < 4; nt++) {
            const int row = wave * 64 + nt * 16 + r16;
            bF[nt] = *(const short8*)(Bc + row * BK + (kq ^ ((row >> 1) & 3)) * 8);
        }
#pragma unroll
        for (int mt = 0; mt < 8; mt++)
#pragma unroll
            for (int nt = 0; nt < 4; nt++)
                acc[mt][nt] = __builtin_amdgcn_mfma_f32_16x16x32_bf16(aF[mt], bF[nt], acc[mt][nt], 0, 0, 0);

        if (pf) {
            *(short8*)(An + arow * ASTRIDE + ah * 16)     = cvt8(xr0, xr1);
            *(short8*)(An + arow * ASTRIDE + ah * 16 + 8) = cvt8(xr2, xr3);
#pragma unroll
            for (int r = 0; r < 4; r++) {
                const int row = r * 64 + brow;
                const int f   = (row >> 1) & 3;
                const float* p = w1f + (size_t)row * D_IN + kk * BK + BK + bc * 8;
                *(short8*)(Bn + row * BK + (bc ^ f) * 8) = cvt8(*(const float4*)p, *(const float4*)(p + 4));
            }
        }
    }

    float b1v[4];
#pragma unroll
    for (int nt = 0; nt < 4; nt++)
        b1v[nt] = b1[m * DIM + half * 256 + wave * 64 + nt * 16 + r16];

    for (int hh = 0; hh < 2; hh++) {
        __syncthreads();
#pragma unroll
        for (int mt2 = 0; mt2 < 4; mt2++) {
            const int mt = hh * 4 + mt2;
#pragma unroll
            for (int nt = 0; nt < 4; nt++) {
#pragma unroll
                for (int reg = 0; reg < 4; reg++) {
                    float v = acc[mt][nt][reg] + b1v[nt];
                    v = v > 0.f ? v : 0.f;
                    const int lr  = mt2 * 16 + kq * 4 + reg;
                    const int col = wave * 64 + nt * 16 + r16;
                    ldsH[lr * HSTRIDE + col] = f2bf(v);
                }
            }
        }
        __syncthreads();

        {
            float4v acc2 = (float4v){0.f, 0.f, 0.f, 0.f};
            const int hrow = wave * 16 + r16;
            const float* w2row = W2 + (size_t)(m * OSZ + r16) * D_IN + m * DIM + half * 256;
#pragma unroll
            for (int kc = 0; kc < 8; kc++) {
                const int c = kc * 32 + kq * 8;
                short8 hA = *(const short8*)(ldsH + hrow * HSTRIDE + c);
                short8 wb = {0, 0, 0, 0, 0, 0, 0, 0};
                if (r16 < OSZ) {
                    const float* p = w2row + c;
                    wb = cvt8(*(const float4*)p, *(const float4*)(p + 4));
                }
                acc2 = __builtin_amdgcn_mfma_f32_16x16x32_bf16(hA, wb, acc2, 0, 0, 0);
            }
            if (r16 < OSZ) {
#pragma unroll
                for (int reg = 0; reg < 4; reg++) {
                    const int grow = rowBase + hh * 64 + wave * 16 + kq * 4 + reg;
                    atomicAdd(out + (size_t)grow * D_OUT + m * OSZ + r16, acc2[reg]);
                }
            }
        }
    }
}

extern "C" void kernel_launch(void* const* d_in, const int* in_sizes, int n_in,
                              void* d_out, int out_size, void* d_ws, size_t ws_size,
                              hipStream_t stream) {
    const float* x  = (const float*)d_in[0];
    const float* W1 = (const float*)d_in[1];
    const float* b1 = (const float*)d_in[2];
    const float* W2 = (const float*)d_in[3];
    const float* b2 = (const float*)d_in[4];
    float* out = (float*)d_out;

    const size_t need = XB_SHORTS * sizeof(ushort) +                       // 64 MB xb
                        (size_t)NMOD * DIM * DIM * sizeof(ushort);         // + 4 MB w1b
    if (ws_size >= need) {                                                 // tier A
        ushort* xb  = (ushort*)d_ws;
        ushort* w1b = xb + XB_SHORTS;
        cvt_x_kernel<<<dim3(XGRAN / 256), dim3(256), 0, stream>>>(x, xb);
        cvt_w_kernel<<<dim3(2048), dim3(256), 0, stream>>>(W1, w1b);
        fused_full2<<<dim3(512), dim3(512), 0, stream>>>(xb, w1b, b1, W2, b2, out);
    } else {                                                               // tier C
        init_out_kernel<<<dim3(2560), dim3(256), 0, stream>>>(b2, out);
        fused_kernel<<<dim3(1024), dim3(256), 0, stream>>>(x, W1, b1, W2, out);
    }
}